// Round 1
// baseline (1586.876 us; speedup 1.0000x reference)
//
#include <hip/hip_runtime.h>
#include <utility>

// E3 Hamiltonian block expansion: out[n, off_b + p*mm + (l*nR+r)] =
//   sum_m cg_b[l,r,m] * in[n, off_b + p*mm + m],  mm = nL*nR (square per run).
//
// Memory-bound: 0.68 GB in + 0.68 GB out -> ~215us floor at 6.3 TB/s.
// Thread = one output column (282 cols over 5 waves of a 320-thread block),
// CG row in registers (loaded once), rows streamed 100 per block.

#define N_EDGE 600000
#define WIDTH 282
#define ROWS_PER_BLOCK 100
#define NBLOCKS (N_EDGE / ROWS_PER_BLOCK)   // 6000, exact

template <int MMC>
__device__ __forceinline__ void row_loop(const float* __restrict__ rp,
                                         float* __restrict__ op,
                                         const float (&cgv)[25], bool valid) {
    for (int r = 0; r < ROWS_PER_BLOCK; ++r) {
        float acc = 0.0f;
#pragma unroll
        for (int m = 0; m < MMC; ++m) {
            acc = fmaf(cgv[m], rp[m], acc);
        }
        if (valid) __builtin_nontemporal_store(acc, op);
        rp += WIDTH;
        op += WIDTH;
    }
}

__global__ __launch_bounds__(320, 4) void e3ham_kernel(
    const float* __restrict__ in,
    const float* __restrict__ cg_ss, const float* __restrict__ cg_sp,
    const float* __restrict__ cg_sd, const float* __restrict__ cg_pp,
    const float* __restrict__ cg_pd, const float* __restrict__ cg_dd,
    float* __restrict__ out)
{
    const int tid = threadIdx.x;
    const bool valid = (tid < WIDTH);
    const int c = valid ? tid : (WIDTH - 1);

    // Column metadata: block ranges (offsets 0,6,33,63,117,207), mm per block,
    // p = local/mm, rr = l*nR + r = local%mm. cg flat index = rr*mm + m.
    int in_base, mm;
    const float* cgp;
    if (c < 6)        { mm = 1;  int l = c;       in_base = 0   + l;                          cgp = cg_ss; }
    else if (c < 33)  { mm = 3;  int l = c - 6;   int q = l/3;  int rr = l - q*3;  in_base = 6   + q*3;  cgp = cg_sp + rr*3;  }
    else if (c < 63)  { mm = 5;  int l = c - 33;  int q = l/5;  int rr = l - q*5;  in_base = 33  + q*5;  cgp = cg_sd + rr*5;  }
    else if (c < 117) { mm = 9;  int l = c - 63;  int q = l/9;  int rr = l - q*9;  in_base = 63  + q*9;  cgp = cg_pp + rr*9;  }
    else if (c < 207) { mm = 15; int l = c - 117; int q = l/15; int rr = l - q*15; in_base = 117 + q*15; cgp = cg_pd + rr*15; }
    else              { mm = 25; int l = c - 207; int q = l/25; int rr = l - q*25; in_base = 207 + q*25; cgp = cg_dd + rr*25; }
    if (!valid) { mm = 0; in_base = 0; }  // harmless in-bounds loads, zero coeffs

    // CG row into registers, zero-padded so the wave-uniform trip count is safe:
    // for m in [mm, wmm) we load in-bounds neighbor data and multiply by 0.
    float cgv[25];
#pragma unroll
    for (int m = 0; m < 25; ++m) cgv[m] = (m < mm) ? cgp[m] : 0.0f;

    // Wave-uniform max mm for this wave's column range (c = tid, contiguous):
    // wave0: c 0..63   -> max 9   (ss/sp/sd/pp)
    // wave1: c 64..127 -> max 15  (pp/pd)
    // wave2: c 128..191-> 15      (pd)
    // wave3: c 192..255-> 25      (pd/dd)
    // wave4: c 256..319-> 25      (dd)
    const int wave = tid >> 6;
    int wmmv = (wave == 0) ? 9 : ((wave < 3) ? 15 : 25);
    const int wmm = __builtin_amdgcn_readfirstlane(wmmv);

    const long long r0 = (long long)blockIdx.x * ROWS_PER_BLOCK;
    const float* rp = in + r0 * WIDTH + in_base;
    float* op = out + r0 * WIDTH + c;

    if (wmm == 9)       row_loop<9>(rp, op, cgv, valid);
    else if (wmm == 15) row_loop<15>(rp, op, cgv, valid);
    else                row_loop<25>(rp, op, cgv, valid);
}

extern "C" void kernel_launch(void* const* d_in, const int* in_sizes, int n_in,
                              void* d_out, int out_size, void* d_ws, size_t ws_size,
                              hipStream_t stream) {
    const float* in    = (const float*)d_in[0];
    const float* cg_ss = (const float*)d_in[1];
    const float* cg_sp = (const float*)d_in[2];
    const float* cg_sd = (const float*)d_in[3];
    const float* cg_pp = (const float*)d_in[4];
    const float* cg_pd = (const float*)d_in[5];
    const float* cg_dd = (const float*)d_in[6];
    float* out = (float*)d_out;

    e3ham_kernel<<<dim3(NBLOCKS), dim3(320), 0, stream>>>(
        in, cg_ss, cg_sp, cg_sd, cg_pp, cg_pd, cg_dd, out);
}